// Round 5
// baseline (195.135 us; speedup 1.0000x reference)
//
#include <hip/hip_runtime.h>

#define HW_ 1024

typedef __attribute__((ext_vector_type(8))) short bf16x8;   // 8 bf16 = 4 VGPRs
typedef __attribute__((ext_vector_type(4))) short bf16x4;   // 8 B
typedef __attribute__((ext_vector_type(4))) float f32x4;

__device__ inline unsigned short f2bf(float f) {            // RNE f32->bf16
  unsigned int u = __float_as_uint(f);
  u += 0x7FFF + ((u >> 16) & 1);
  return (unsigned short)(u >> 16);
}
__device__ inline unsigned short f2bf_fast(float f) {       // ties-away (2 ops)
  return (unsigned short)((__float_as_uint(f) + 0x8000u) >> 16);
}
__device__ inline float bf2f(unsigned short h) {
  return __uint_as_float(((unsigned int)h) << 16);
}
__device__ inline void async_copy16(const void* g, void* l) {
  __builtin_amdgcn_global_load_lds(
      (const __attribute__((address_space(1))) unsigned int*)g,
      (__attribute__((address_space(3))) unsigned int*)l, 16, 0, 0);
}

// ---------------------------------------------------------------------------
// fused0 = prep + Q-GEMM in one kernel (grid 1248):
//   [0,512)    Q-GEMM M-half blocks; A-fragments split from f32 Wq on the fly.
//   [512,768)  kvT transpose (b,c,p)->(b,p,c).
//   [768,960)  wsplit Wk/Wv/Wout -> WH/WL slots 1..3.
//   [960,1248) conv weight repack -> wb.
// ---------------------------------------------------------------------------
__global__ __launch_bounds__(256) void fused0(
    const float* __restrict__ kv,
    const float* __restrict__ Wq, const float* __restrict__ Wk,
    const float* __restrict__ Wv, const float* __restrict__ Wo,
    const float* __restrict__ Woff1, const float* __restrict__ Xf,
    short* __restrict__ WH, short* __restrict__ WL, short* __restrict__ wb,
    float* __restrict__ kvT,
    short* __restrict__ Yt, short* __restrict__ Yh2, short* __restrict__ Yl2)
{
  __shared__ float T[256][33];          // kvT path
  __shared__ short Bsh[32][40];         // gemm path
  __shared__ short Bsl[32][40];
  const int bid = blockIdx.x, t = threadIdx.x;

  if (bid < 512) {                      // ---- Q-GEMM (MODE 0) ----
    const int w    = t >> 6;
    const int lane = t & 63;
    const int ln   = lane & 15;
    const int qd   = lane >> 4;
    const int bp0  = (bid & 255) * 32;
    const int om   = (bid >> 8) * 128 + w * 32;
    const int bB   = bp0 >> 10, p0l = bp0 & 1023;

    f32x4 acc[2][2] = {};
#pragma unroll
    for (int k0 = 0; k0 < 256; k0 += 32) {
      __syncthreads();
      {                                 // stage + split X tile
        int pp = t & 31, cg = t >> 5;
        float fv[4];
#pragma unroll
        for (int j = 0; j < 4; ++j)
          fv[j] = Xf[((size_t)(bB * 256 + k0 + cg * 4 + j)) * HW_ + p0l + pp];
        bf16x4 h4, l4;
#pragma unroll
        for (int j = 0; j < 4; ++j) {
          unsigned short h = f2bf(fv[j]);
          h4[j] = (short)h;
          l4[j] = (short)f2bf(fv[j] - bf2f(h));
        }
        *(bf16x4*)&Bsh[pp][cg * 4] = h4;
        *(bf16x4*)&Bsl[pp][cg * 4] = l4;
      }
      __syncthreads();

      bf16x8 Ah[2], Al[2], Bh[2], Bl[2];
#pragma unroll
      for (int mt = 0; mt < 2; ++mt) {  // on-the-fly Wq split
        const float* ws = &Wq[((size_t)(om + mt * 16 + ln)) * 256 + k0 + qd * 8];
        float4 fa = *(const float4*)ws;
        float4 fb = *(const float4*)(ws + 4);
        float f8[8] = {fa.x, fa.y, fa.z, fa.w, fb.x, fb.y, fb.z, fb.w};
#pragma unroll
        for (int j = 0; j < 8; ++j) {
          unsigned short h = f2bf(f8[j]);
          Ah[mt][j] = (short)h;
          Al[mt][j] = (short)f2bf(f8[j] - bf2f(h));
        }
      }
#pragma unroll
      for (int nt = 0; nt < 2; ++nt) {
        Bh[nt] = *(const bf16x8*)&Bsh[nt * 16 + ln][qd * 8];
        Bl[nt] = *(const bf16x8*)&Bsl[nt * 16 + ln][qd * 8];
      }
#pragma unroll
      for (int mt = 0; mt < 2; ++mt)
#pragma unroll
        for (int nt = 0; nt < 2; ++nt) {
          acc[mt][nt] = __builtin_amdgcn_mfma_f32_16x16x32_bf16(Ah[mt], Bh[nt], acc[mt][nt], 0, 0, 0);
          acc[mt][nt] = __builtin_amdgcn_mfma_f32_16x16x32_bf16(Ah[mt], Bl[nt], acc[mt][nt], 0, 0, 0);
          acc[mt][nt] = __builtin_amdgcn_mfma_f32_16x16x32_bf16(Al[mt], Bh[nt], acc[mt][nt], 0, 0, 0);
        }
    }

    const float sc = 0.25506063286f;   // (1/sqrt32)*log2(e)
#pragma unroll
    for (int mt = 0; mt < 2; ++mt)
#pragma unroll
      for (int nt = 0; nt < 2; ++nt) {
        int bp = bp0 + nt * 16 + ln;
        int b = bp >> 10, p = bp & 1023;
#pragma unroll
        for (int i = 0; i < 4; ++i) {
          int o = om + mt * 16 + qd * 4 + i;
          int h = o >> 5, d = o & 31;
          Yt[(((size_t)(b * 8 + h)) * 1024 + p) * 32 + d] = (short)f2bf(acc[mt][nt][i] * sc);
        }
        int ob = om + mt * 16 + qd * 4;
        bf16x4 h4, l4;
#pragma unroll
        for (int i = 0; i < 4; ++i) {
          float f = acc[mt][nt][i];
          unsigned short h = f2bf(f);
          h4[i] = (short)h;
          l4[i] = (short)f2bf(f - bf2f(h));
        }
        *(bf16x4*)&Yh2[(size_t)bp * 256 + ob] = h4;
        *(bf16x4*)&Yl2[(size_t)bp * 256 + ob] = l4;
      }

  } else if (bid < 768) {               // ---- kvT transpose ----
    int tb = bid - 512;
    int b = tb >> 5, p0 = (tb & 31) * 32;
    int pp = t & 31, cg = t >> 5;
#pragma unroll
    for (int i = 0; i < 32; ++i) {
      int c = cg * 32 + i;
      T[c][pp] = kv[((size_t)(b * 256 + c)) * HW_ + p0 + pp];
    }
    __syncthreads();
#pragma unroll
    for (int r = 0; r < 8; ++r) {
      int e = t + 256 * r;
      int c4 = (e & 63) * 4, pp2 = e >> 6;
      float4 v4;
      v4.x = T[c4 + 0][pp2];
      v4.y = T[c4 + 1][pp2];
      v4.z = T[c4 + 2][pp2];
      v4.w = T[c4 + 3][pp2];
      *(float4*)&kvT[((size_t)(b * 1024 + p0 + pp2)) * 256 + c4] = v4;
    }
  } else if (bid < 960) {               // ---- wsplit Wk/Wv/Wout ----
    int b2 = bid - 768;
    int mat = b2 >> 6;
    int loc = (b2 & 63) * 1024 + t * 4;
    const float* W = (mat == 0) ? Wk : (mat == 1) ? Wv : Wo;
    float4 f4 = *(const float4*)&W[loc];
    float f[4] = {f4.x, f4.y, f4.z, f4.w};
    bf16x4 h4, l4;
#pragma unroll
    for (int j = 0; j < 4; ++j) {
      unsigned short h = f2bf(f[j]);
      h4[j] = (short)h;
      l4[j] = (short)f2bf(f[j] - bf2f(h));
    }
    *(bf16x4*)&WH[(mat + 1) * 65536 + loc] = h4;
    *(bf16x4*)&WL[(mat + 1) * 65536 + loc] = l4;
  } else {                              // ---- conv weight repack ----
    int e0 = (bid - 960) * 1024 + t * 4;
#pragma unroll
    for (int j = 0; j < 4; ++j) {
      int e = e0 + j;
      int c = e & 255;
      int o = (e >> 8) & 127;
      int tap = e >> 15;
      wb[e] = (short)f2bf(Woff1[((size_t)(o * 256 + c)) * 9 + tap]);
    }
  }
}

// ---------------------------------------------------------------------------
// convkv v3: conv3x3 + offset head + sampling + K/V GEMM, one kernel.
// v2 post-mortem: 44.8 us at Occupancy 19% -- LATENCY-bound at 2 waves/SIMD
// (1 block/CU, 512 thr). v3: 1024 threads (16 waves, 4 waves/SIMD) with
// traffic-neutral work splits:
//  * conv: 16 waves = 2 x-halves x 2 c-halves x 4 o-groups. Block ds_reads
//    1152 (same as v2); wb footprint/block 589 KB (same).
//  * KV GEMM: 16 waves = 2 mats x 8 M-groups (mt=2,nt=2); weight traffic same.
//  * coords summation order bit-identical to v2.
// grid 256 (b = id&7 -> XCD-local), LDS 139.5 KB, 1 block/CU, 16 waves/CU.
// ---------------------------------------------------------------------------
__global__ __launch_bounds__(1024) void convkv(
    const short* __restrict__ wb, const float* __restrict__ bias,
    const float* __restrict__ W2, const float* __restrict__ b2,
    const short* __restrict__ xh, const short* __restrict__ xl,
    const float* __restrict__ kvT,
    const short* __restrict__ WH, const short* __restrict__ WL,
    short* __restrict__ kt, short* __restrict__ vt)
{
  __shared__ short Xs[2][3][34][264];   // full strip, ch-pad 264 (528B rows)
  __shared__ short XsH[32][264];
  __shared__ short XsL[32][264];
  __shared__ float red[4][32][2];
  __shared__ float2 crd[32];
  const int id   = blockIdx.x;          // 256
  const int b    = id & 7;
  const int y0   = id >> 3;             // 0..31
  const int t    = threadIdx.x;
  const int w    = t >> 6;              // 0..15
  const int lane = t & 63;
  const int ln   = lane & 15;
  const int qd   = lane >> 4;
  const int bp0  = (b * 32 + y0) * 32;  // global pixel-row base

  // ---------------- phase 0: one-shot staging ----------------
  {
    bf16x8 v[6];
#pragma unroll
    for (int i = 0; i < 6; ++i) {       // 6144 tasks: hl,r,x,oct
      int e = t + 1024 * i;
      int oct = e & 31;
      int x   = (e >> 5) & 31;
      int rr  = e >> 10;                // 0..5
      int hl  = rr / 3, r = rr % 3;
      int yy  = y0 + r - 1;
      bf16x8 val = {};
      if (yy >= 0 && yy < 32) {
        const short* src = hl ? xl : xh;
        val = *(const bf16x8*)&src[((size_t)((b * 32 + yy) * 32 + x)) * 256 + oct * 8];
      }
      v[i] = val;
    }
#pragma unroll
    for (int i = 0; i < 6; ++i) {
      int e = t + 1024 * i;
      int oct = e & 31;
      int x   = (e >> 5) & 31;
      int rr  = e >> 10;
      int hl  = rr / 3, r = rr % 3;
      *(bf16x8*)&Xs[hl][r][x + 1][oct * 8] = v[i];
    }
    if (t < 384) {                      // zero columns x=0 and x=33
      int oct  = t & 31;
      int colw = (t >> 5) & 1;
      int rr   = t >> 6;                // 0..5
      int hl   = rr / 3, r = rr % 3;
      bf16x8 zz = {};
      *(bf16x8*)&Xs[hl][r][colw ? 33 : 0][oct * 8] = zz;
    }
  }
  __syncthreads();

  // -------- phase 1: conv3x3, 2 x-halves x 2 c-halves x 4 o-groups --------
  const int xph = w >> 3;               // x-half 0/1
  const int chh = (w >> 2) & 1;         // c-half 0/1
  const int ow  = w & 3;                // o-group (32 o's)
  const int o0c = ow * 32;
  f32x4 acc[2] = {};                    // m = 0,1 (16 o's each); 16 px = ln
#pragma unroll
  for (int c0s = 0; c0s < 4; ++c0s) {
    const int c0 = chh * 128 + c0s * 32;
#pragma unroll
    for (int tap = 0; tap < 9; ++tap) {
      const int ky = tap / 3, kx = tap % 3;
      bf16x8 afr[2];
#pragma unroll
      for (int m = 0; m < 2; ++m)
        afr[m] = *(const bf16x8*)&wb[((size_t)(tap * 128 + o0c + m * 16 + ln)) * 256
                                     + c0 + qd * 8];
      int hc = xph * 16 + ln + kx;
      bf16x8 bh = *(const bf16x8*)&Xs[0][ky][hc][c0 + qd * 8];
      bf16x8 bl = *(const bf16x8*)&Xs[1][ky][hc][c0 + qd * 8];
#pragma unroll
      for (int m = 0; m < 2; ++m) {
        acc[m] = __builtin_amdgcn_mfma_f32_16x16x32_bf16(afr[m], bh, acc[m], 0, 0, 0);
        acc[m] = __builtin_amdgcn_mfma_f32_16x16x32_bf16(afr[m], bl, acc[m], 0, 0, 0);
      }
    }
  }

  // combine c-halves: chh=1 waves park partials in XsH overlay (16 KB)
  float* ps = (float*)&XsH[0][0];
  const int slot = xph * 4 + ow;        // 0..7
  if (chh == 1) {
#pragma unroll
    for (int m = 0; m < 2; ++m)
      *(f32x4*)&ps[((slot * 64 + lane) * 2 + m) * 4] = acc[m];
  }
  __syncthreads();

  // ---------------- phase 2: offset head -> coords (chh==0 waves) ----------
  if (chh == 0) {
    float ps0 = 0.f, ps1 = 0.f;
#pragma unroll
    for (int m = 0; m < 2; ++m) {
      f32x4 p = *(const f32x4*)&ps[((slot * 64 + lane) * 2 + m) * 4];
      acc[m] += p;
    }
#pragma unroll
    for (int m = 0; m < 2; ++m)
#pragma unroll
      for (int i = 0; i < 4; ++i) {
        int o = o0c + m * 16 + qd * 4 + i;
        float bo = bias[o];
        float w2a = W2[o], w2b = W2[128 + o];
        float h = fmaxf(acc[m][i] + bo, 0.f);
        ps0 += w2a * h;
        ps1 += w2b * h;
      }
#pragma unroll
    for (int msk = 16; msk < 64; msk <<= 1) {
      ps0 += __shfl_xor(ps0, msk, 64);
      ps1 += __shfl_xor(ps1, msk, 64);
    }
    if (qd == 0) {
      red[ow][xph * 16 + ln][0] = ps0;
      red[ow][xph * 16 + ln][1] = ps1;
    }
  }
  __syncthreads();
  if (t < 32) {
    float c0s = (red[0][t][0] + red[1][t][0]) + (red[2][t][0] + red[3][t][0]) + b2[0];
    float c1s = (red[0][t][1] + red[1][t][1]) + (red[2][t][1] + red[3][t][1]) + b2[1];
    float gx = -1.f + 2.f * (float)t / 31.f;
    float gy = -1.f + 2.f * (float)y0 / 31.f;
    float vx = gx + 0.1f * c0s;
    float vy = gy + 0.1f * c1s;
    float px = fminf(fmaxf((vx + 1.f) * 0.5f * 31.f, 0.f), 31.f);
    float py = fminf(fmaxf((vy + 1.f) * 0.5f * 31.f, 0.f), 31.f);
    crd[t] = make_float2(px, py);
  }
  __syncthreads();

  // ---------------- phase 3: sampling + K/V GEMM ----------------
  {
    int e = t;                         // 1024 tasks: 32 rows x 32 octs
    int oct = e & 31, row = e >> 5;
    float2 cd = crd[row];
    float x0f = floorf(cd.x), y0f = floorf(cd.y);
    float wx = cd.x - x0f, wy = cd.y - y0f;
    int x0 = (int)x0f, y0i = (int)y0f;
    int x1 = min(x0 + 1, 31), y1 = min(y0i + 1, 31);
    float w00 = (1.f - wx) * (1.f - wy), w01 = wx * (1.f - wy);
    float w10 = (1.f - wx) * wy,         w11 = wx * wy;
    const float* r00 = &kvT[((size_t)(b * 1024 + y0i * 32 + x0)) * 256 + oct * 8];
    const float* r01 = &kvT[((size_t)(b * 1024 + y0i * 32 + x1)) * 256 + oct * 8];
    const float* r10 = &kvT[((size_t)(b * 1024 + y1 * 32 + x0)) * 256 + oct * 8];
    const float* r11 = &kvT[((size_t)(b * 1024 + y1 * 32 + x1)) * 256 + oct * 8];
    float4 a00 = *(const float4*)r00, b00 = *(const float4*)(r00 + 4);
    float4 a01 = *(const float4*)r01, b01 = *(const float4*)(r01 + 4);
    float4 a10 = *(const float4*)r10, b10 = *(const float4*)(r10 + 4);
    float4 a11 = *(const float4*)r11, b11 = *(const float4*)(r11 + 4);
    float v[8];
    v[0] = a00.x * w00 + a01.x * w01 + a10.x * w10 + a11.x * w11;
    v[1] = a00.y * w00 + a01.y * w01 + a10.y * w10 + a11.y * w11;
    v[2] = a00.z * w00 + a01.z * w01 + a10.z * w10 + a11.z * w11;
    v[3] = a00.w * w00 + a01.w * w01 + a10.w * w10 + a11.w * w11;
    v[4] = b00.x * w00 + b01.x * w01 + b10.x * w10 + b11.x * w11;
    v[5] = b00.y * w00 + b01.y * w01 + b10.y * w10 + b11.y * w11;
    v[6] = b00.z * w00 + b01.z * w01 + b10.z * w10 + b11.z * w11;
    v[7] = b00.w * w00 + b01.w * w01 + b10.w * w10 + b11.w * w11;
    bf16x8 h8, l8;
#pragma unroll
    for (int j = 0; j < 8; ++j) {
      unsigned short h = f2bf(v[j]);
      h8[j] = (short)h;
      l8[j] = (short)f2bf(v[j] - bf2f(h));
    }
    *(bf16x8*)&XsH[row][oct * 8] = h8;
    *(bf16x8*)&XsL[row][oct * 8] = l8;
  }
  __syncthreads();

  const int mat = w >> 3;              // waves 0-7 = K, 8-15 = V
  const short* WAh = WH + (mat ? 131072 : 65536);   // Wv : Wk (bf16 hi)
  const short* WAl = WL + (mat ? 131072 : 65536);
  const int om = (w & 7) * 32;         // wave covers 32 of the 256 rows

  f32x4 acg[2][2] = {};
#pragma unroll
  for (int k0 = 0; k0 < 256; k0 += 32) {
    bf16x8 Bh[2], Bl[2];
#pragma unroll
    for (int nt = 0; nt < 2; ++nt) {
      Bh[nt] = *(const bf16x8*)&XsH[nt * 16 + ln][k0 + qd * 8];
      Bl[nt] = *(const bf16x8*)&XsL[nt * 16 + ln][k0 + qd * 8];
    }
#pragma unroll
    for (int mt = 0; mt < 2; ++mt) {
      size_t wi = ((size_t)(om + mt * 16 + ln)) * 256 + k0 + qd * 8;
      bf16x8 Ah = *(const bf16x8*)&WAh[wi];
      bf16x8 Al = *(const bf16x8*)&WAl[wi];
#pragma unroll
      for (int nt = 0; nt < 2; ++nt) {
        acg[mt][nt] = __builtin_amdgcn_mfma_f32_16x16x32_bf16(Ah, Bh[nt], acg[mt][nt], 0, 0, 0);
        acg[mt][nt] = __builtin_amdgcn_mfma_f32_16x16x32_bf16(Ah, Bl[nt], acg[mt][nt], 0, 0, 0);
        acg[mt][nt] = __builtin_amdgcn_mfma_f32_16x16x32_bf16(Al, Bh[nt], acg[mt][nt], 0, 0, 0);
      }
    }
  }

#pragma unroll
  for (int mt = 0; mt < 2; ++mt)
#pragma unroll
    for (int nt = 0; nt < 2; ++nt) {
      int p  = bp0 + nt * 16 + ln;
      int pl = p & 1023;
      int jt = pl >> 6, jl = pl & 63;
#pragma unroll
      for (int i = 0; i < 4; ++i) {
        int oc = om + mt * 16 + qd * 4 + i;
        unsigned short val = f2bf(acg[mt][nt][i]);
        int bhead = b * 8 + (oc >> 5), d = oc & 31;
        if (mat == 0) {
          int cd2 = (d >> 3) ^ ((jl >> 2) & 3);
          kt[((((size_t)(bhead * 16 + jt)) * 64 + jl) * 4 + cd2) * 8 + (d & 7)] = (short)val;
        } else {
          int jjs = ((jl & 15) << 2) | (jl >> 4);       // sigma
          int cj = (jjs >> 3) ^ (d & 7);
          vt[((((size_t)(bhead * 16 + jt)) * 32 + d) * 8 + cj) * 8 + (jjs & 7)] = (short)val;
        }
      }
    }
}

// ---------------------------------------------------------------------------
// MFMA flash attention, async LDS double-buffered K/V.
// 2x Q-TILE per wave; XCD swizzle b = id&7; setprio around MFMA clusters.
// ---------------------------------------------------------------------------
__global__ __launch_bounds__(256) void attn_mfma(
    const short* __restrict__ qt, const short* __restrict__ kt,
    const short* __restrict__ vt, short* __restrict__ aoh,
    short* __restrict__ aol)
{
  __shared__ __align__(16) short Ks[2][2048];
  __shared__ __align__(16) short Vs[2][2048];
  __shared__ __align__(16) short P[4][32][72];
  const int t    = threadIdx.x;
  const int w    = t >> 6;
  const int lane = t & 63;
  const int ln   = lane & 15;
  const int qd   = lane >> 4;
  const int id   = blockIdx.x;          // 512
  const int b    = id & 7;
  const int rem  = id >> 3;             // 0..63
  const int h    = rem & 7;
  const int qc   = rem >> 3;            // 0..7
  const int bh   = b * 8 + h;
  const int qbase = qc * 128 + w * 16;  // fragment 0; fragment 1 at +64

  const short* ktb = kt + (size_t)bh * 32768;
  const short* vtb = vt + (size_t)bh * 32768;

  bf16x8 aq[2];
  aq[0] = *(const bf16x8*)&qt[((size_t)(bh * 1024 + qbase + ln)) * 32 + qd * 8];
  aq[1] = *(const bf16x8*)&qt[((size_t)(bh * 1024 + qbase + 64 + ln)) * 32 + qd * 8];

  f32x4 acc[2][2] = {};
  float lacc[2][4] = {};
  const f32x4 zero = {0.f, 0.f, 0.f, 0.f};

  const int stoff = w * 512 + lane * 8;
  const int ldoff = w * 512;

  async_copy16(&ktb[stoff], &Ks[0][ldoff]);
  async_copy16(&vtb[stoff], &Vs[0][ldoff]);
  __syncthreads();

  for (int jt = 0; jt < 16; ++jt) {
    const int cur = jt & 1, nxt = cur ^ 1;
    if (jt < 15) {
      async_copy16(&ktb[(jt + 1) * 2048 + stoff], &Ks[nxt][ldoff]);
      async_copy16(&vtb[(jt + 1) * 2048 + stoff], &Vs[nxt][ldoff]);
    }

    bf16x8 bk[4], bv[2][2];
#pragma unroll
    for (int kk = 0; kk < 4; ++kk)
      bk[kk] = *(const bf16x8*)&Ks[cur][((kk * 16 + ln) * 4 + (qd ^ ((ln >> 2) & 3))) * 8];
#pragma unroll
    for (int kc = 0; kc < 2; ++kc)
#pragma unroll
      for (int ds = 0; ds < 2; ++ds)
        bv[kc][ds] = *(const bf16x8*)&Vs[cur][((ds * 16 + ln) * 8 + ((kc * 4 + qd) ^ (ln & 7))) * 8];

#pragma unroll
    for (int qf = 0; qf < 2; ++qf) {
      f32x4 s[4];
      __builtin_amdgcn_s_setprio(1);
#pragma unroll
      for (int kk = 0; kk < 4; ++kk)
        s[kk] = __builtin_amdgcn_mfma_f32_16x16x32_bf16(aq[qf], bk[kk], zero, 0, 0, 0);
      __builtin_amdgcn_s_setprio(0);

#pragma unroll
      for (int i = 0; i < 4; ++i) {
        float p0 = __builtin_amdgcn_exp2f(s[0][i]);
        float p1 = __builtin_amdgcn_exp2f(s[1][i]);
        float p2 = __builtin_amdgcn_exp2f(s[2][i]);
        float p3 = __builtin_amdgcn_exp2f(s[3][i]);
        s[0][i] = p0; s[1][i] = p1; s[2][i] = p2; s[3][i] = p3;
        lacc[qf][i] += (p0 + p1) + (p2 + p3);
      }
#pragma unroll
      for (int i = 0; i < 4; ++i) {
        bf16x4 p4;
#pragma unroll
        for (int kk = 0; kk < 4; ++kk) p4[kk] = (short)f2bf_fast(s[kk][i]);
        *(bf16x4*)&P[w][qf * 16 + qd * 4 + i][4 * ln] = p4;
      }
      __builtin_amdgcn_s_setprio(1);
#pragma unroll
      for (int kc = 0; kc < 2; ++kc) {
        bf16x8 ap = *(const bf16x8*)&P[w][qf * 16 + ln][kc * 32 + qd * 8];
#pragma unroll
        for (int ds = 0; ds < 2; ++ds)
          acc[qf][ds] = __builtin_amdgcn_mfma_f32_16x16x32_bf16(ap, bv[kc][ds], acc[qf][ds], 0, 0, 0);
      }
      __builtin_amdgcn_s_setprio(0);
    }

    __syncthreads();
  }

  const int bb = bh >> 3, hh2 = bh & 7;
#pragma unroll
  for (int qf = 0; qf < 2; ++qf)
#pragma unroll
    for (int i = 0; i < 4; ++i) {
      float l = lacc[qf][i];
      l += __shfl_xor(l, 1, 64);
      l += __shfl_xor(l, 2, 64);
      l += __shfl_xor(l, 4, 64);
      l += __shfl_xor(l, 8, 64);
      float inv = 1.f / l;
      int qrow = qbase + qf * 64 + qd * 4 + i;
#pragma unroll
      for (int ds = 0; ds < 2; ++ds) {
        float v = acc[qf][ds][i] * inv;
        unsigned short hv = f2bf(v);
        size_t idx = ((size_t)(bb * 1024 + qrow)) * 256 + hh2 * 32 + ds * 16 + ln;
        aoh[idx] = (short)hv;
        aol[idx] = (short)f2bf(v - bf2f(hv));
      }
    }
}

// ---------------------------------------------------------------------------
// Output GEMM (Wout), LDS-free, f32 out + bias. grid (256,2).
// ---------------------------------------------------------------------------
__global__ __launch_bounds__(256) void gemm_out(
    const short* __restrict__ Wh, const short* __restrict__ Wl,
    const short* __restrict__ Xh, const short* __restrict__ Xl,
    const float* __restrict__ bias, float* __restrict__ Yf)
{
  const int t    = threadIdx.x;
  const int w    = t >> 6;
  const int lane = t & 63;
  const int ln   = lane & 15;
  const int qd   = lane >> 4;
  const int bp0  = blockIdx.x * 32;
  const int om   = blockIdx.y * 128 + w * 32;

  f32x4 acc[2][2] = {};
#pragma unroll
  for (int k0 = 0; k0 < 256; k0 += 32) {
    bf16x8 Ah[2], Al[2], Bh[2], Bl[2];
#pragma unroll
    for (int mt = 0; mt < 2; ++mt) {
      size_t wi = ((size_t)(om + mt * 16 + ln)) * 256 + k0 + qd * 8;
      Ah[mt] = *(const bf16x8*)&Wh[wi];
      Al[mt] = *(const bf16x8*)&Wl[wi];
    }
#pragma unroll
    for (int nt = 0; nt < 2; ++nt) {
      size_t xi = ((size_t)(bp0 + nt * 16 + ln)) * 256 + k0 + qd * 8;
      Bh[nt] = *(const bf16x8*)&Xh[xi];
      Bl[nt] = *(const bf16x8*)&Xl[xi];
    }
#pragma unroll
    for (int mt = 0; mt < 2; ++mt)
#pragma unroll
      for (int nt = 0; nt < 2; ++nt) {
        acc[mt][nt] = __builtin_amdgcn_mfma_f32_16x16x32_bf16(Ah[mt], Bh[nt], acc[mt][nt], 0, 0, 0);
        acc[mt][nt] = __builtin_amdgcn_mfma_f32_16x16x32_bf16(Ah[mt], Bl[nt], acc[mt][nt], 0, 0, 0);
        acc[mt][nt] = __builtin_amdgcn_mfma_f32_16x16x32_bf16(Al[mt], Bh[nt], acc[mt][nt], 0, 0, 0);
      }
  }

#pragma unroll
  for (int mt = 0; mt < 2; ++mt)
#pragma unroll
    for (int i = 0; i < 4; ++i) {
      int o = om + mt * 16 + qd * 4 + i;
      float bo = bias[o];
#pragma unroll
      for (int nt = 0; nt < 2; ++nt) {
        int bp = bp0 + nt * 16 + ln;
        int b = bp >> 10, p = bp & 1023;
        Yf[((size_t)(b * 256 + o)) * HW_ + p] = acc[mt][nt][i] + bo;
      }
    }
}

// ---------------------------------------------------------------------------
extern "C" void kernel_launch(void* const* d_in, const int* in_sizes, int n_in,
                              void* d_out, int out_size, void* d_ws, size_t ws_size,
                              hipStream_t stream)
{
  const float* query_map = (const float*)d_in[0];
  const float* kv_map    = (const float*)d_in[1];
  const float* Wq        = (const float*)d_in[2];
  const float* Wk        = (const float*)d_in[3];
  const float* Wv        = (const float*)d_in[4];
  const float* Woff1     = (const float*)d_in[5];
  const float* boff1     = (const float*)d_in[6];
  const float* Woff2     = (const float*)d_in[7];
  const float* boff2     = (const float*)d_in[8];
  const float* Wout      = (const float*)d_in[9];
  const float* bout      = (const float*)d_in[10];
  float* out = (float*)d_out;
  char* base = (char*)d_ws;

  const size_t MB = 1u << 20;
  short* qt     = (short*)(base + 1 * MB);     // 4 MB (bh,p,d) pre-scaled
  short* kt     = (short*)(base + 5 * MB);     // 4 MB tiled+swizzled
  short* vt     = (short*)(base + 9 * MB);     // 4 MB tiled+swizzled
  short* bufBh  = (short*)(base + 13 * MB);    // 4 MB q hi -> ao hi
  short* bufBl  = (short*)(base + 17 * MB);    // 4 MB q lo -> ao lo
  short* wb     = (short*)(base + 21 * MB);    // 576 KB conv weights bf16
  short* WH     = (short*)(base + 22 * MB);    // 512 KB [unused|Wk|Wv|Wout] hi
  short* WL     = (short*)(base + 23 * MB);    // 512 KB lo
  float* kvT    = (float*)(base + 24 * MB);    // 8 MB kv_map (b,p,c) f32

  fused0<<<dim3(1248), dim3(256), 0, stream>>>(kv_map, Wq, Wk, Wv, Wout, Woff1,
                                               query_map, WH, WL, wb, kvT,
                                               qt, bufBh, bufBl);
  convkv<<<dim3(256), dim3(1024), 0, stream>>>(wb, boff1, Woff2, boff2,
                                               bufBh, bufBl, kvT, WH, WL, kt, vt);
  attn_mfma<<<dim3(512), dim3(256), 0, stream>>>(qt, kt, vt, bufBh, bufBl);
  gemm_out<<<dim3(256, 2), dim3(256), 0, stream>>>(WH + 196608, WL + 196608,
                                                   bufBh, bufBl, bout, out);
}

// Round 6
// 170.992 us; speedup vs baseline: 1.1412x; 1.1412x over previous
//
#include <hip/hip_runtime.h>

#define HW_ 1024

typedef __attribute__((ext_vector_type(8))) short bf16x8;   // 8 bf16 = 4 VGPRs
typedef __attribute__((ext_vector_type(4))) short bf16x4;   // 8 B
typedef __attribute__((ext_vector_type(4))) float f32x4;

__device__ inline unsigned short f2bf(float f) {            // RNE f32->bf16
  unsigned int u = __float_as_uint(f);
  u += 0x7FFF + ((u >> 16) & 1);
  return (unsigned short)(u >> 16);
}
__device__ inline unsigned short f2bf_fast(float f) {       // ties-away (2 ops)
  return (unsigned short)((__float_as_uint(f) + 0x8000u) >> 16);
}
__device__ inline float bf2f(unsigned short h) {
  return __uint_as_float(((unsigned int)h) << 16);
}
__device__ inline void async_copy16(const void* g, void* l) {
  __builtin_amdgcn_global_load_lds(
      (const __attribute__((address_space(1))) unsigned int*)g,
      (__attribute__((address_space(3))) unsigned int*)l, 16, 0, 0);
}

// ---------------------------------------------------------------------------
// fused0 = prep + Q-GEMM in one kernel (grid 1248):
//   [0,512)    Q-GEMM M-half blocks; A-fragments split from f32 Wq on the fly.
//   [512,768)  kvT transpose (b,c,p)->(b,p,c).
//   [768,960)  wsplit: Wk/Wv -> PACKED fragment layout (slots 1,2);
//              Wout -> linear (slot 3).
//   [960,1248) conv weight repack -> wb PACKED [tap][otile][c0s][lane][8].
// Packed layout: a wave's A-fragment load = base + lane*16B, one dense 1 KB
// read (8 seq lines) instead of a 16-row x 64B gather (16 lines). R5 showed
// the gather is convkv's serialized cost (~28 ns/load marginal).
// ---------------------------------------------------------------------------
__global__ __launch_bounds__(256) void fused0(
    const float* __restrict__ kv,
    const float* __restrict__ Wq, const float* __restrict__ Wk,
    const float* __restrict__ Wv, const float* __restrict__ Wo,
    const float* __restrict__ Woff1, const float* __restrict__ Xf,
    short* __restrict__ WH, short* __restrict__ WL, short* __restrict__ wb,
    float* __restrict__ kvT,
    short* __restrict__ Yt, short* __restrict__ Yh2, short* __restrict__ Yl2)
{
  __shared__ float T[256][33];          // kvT path
  __shared__ short Bsh[32][40];         // gemm path
  __shared__ short Bsl[32][40];
  const int bid = blockIdx.x, t = threadIdx.x;

  if (bid < 512) {                      // ---- Q-GEMM (MODE 0) ----
    const int w    = t >> 6;
    const int lane = t & 63;
    const int ln   = lane & 15;
    const int qd   = lane >> 4;
    const int bp0  = (bid & 255) * 32;
    const int om   = (bid >> 8) * 128 + w * 32;
    const int bB   = bp0 >> 10, p0l = bp0 & 1023;

    f32x4 acc[2][2] = {};
#pragma unroll
    for (int k0 = 0; k0 < 256; k0 += 32) {
      __syncthreads();
      {                                 // stage + split X tile
        int pp = t & 31, cg = t >> 5;
        float fv[4];
#pragma unroll
        for (int j = 0; j < 4; ++j)
          fv[j] = Xf[((size_t)(bB * 256 + k0 + cg * 4 + j)) * HW_ + p0l + pp];
        bf16x4 h4, l4;
#pragma unroll
        for (int j = 0; j < 4; ++j) {
          unsigned short h = f2bf(fv[j]);
          h4[j] = (short)h;
          l4[j] = (short)f2bf(fv[j] - bf2f(h));
        }
        *(bf16x4*)&Bsh[pp][cg * 4] = h4;
        *(bf16x4*)&Bsl[pp][cg * 4] = l4;
      }
      __syncthreads();

      bf16x8 Ah[2], Al[2], Bh[2], Bl[2];
#pragma unroll
      for (int mt = 0; mt < 2; ++mt) {  // on-the-fly Wq split
        const float* ws = &Wq[((size_t)(om + mt * 16 + ln)) * 256 + k0 + qd * 8];
        float4 fa = *(const float4*)ws;
        float4 fb = *(const float4*)(ws + 4);
        float f8[8] = {fa.x, fa.y, fa.z, fa.w, fb.x, fb.y, fb.z, fb.w};
#pragma unroll
        for (int j = 0; j < 8; ++j) {
          unsigned short h = f2bf(f8[j]);
          Ah[mt][j] = (short)h;
          Al[mt][j] = (short)f2bf(f8[j] - bf2f(h));
        }
      }
#pragma unroll
      for (int nt = 0; nt < 2; ++nt) {
        Bh[nt] = *(const bf16x8*)&Bsh[nt * 16 + ln][qd * 8];
        Bl[nt] = *(const bf16x8*)&Bsl[nt * 16 + ln][qd * 8];
      }
#pragma unroll
      for (int mt = 0; mt < 2; ++mt)
#pragma unroll
        for (int nt = 0; nt < 2; ++nt) {
          acc[mt][nt] = __builtin_amdgcn_mfma_f32_16x16x32_bf16(Ah[mt], Bh[nt], acc[mt][nt], 0, 0, 0);
          acc[mt][nt] = __builtin_amdgcn_mfma_f32_16x16x32_bf16(Ah[mt], Bl[nt], acc[mt][nt], 0, 0, 0);
          acc[mt][nt] = __builtin_amdgcn_mfma_f32_16x16x32_bf16(Al[mt], Bh[nt], acc[mt][nt], 0, 0, 0);
        }
    }

    const float sc = 0.25506063286f;   // (1/sqrt32)*log2(e)
#pragma unroll
    for (int mt = 0; mt < 2; ++mt)
#pragma unroll
      for (int nt = 0; nt < 2; ++nt) {
        int bp = bp0 + nt * 16 + ln;
        int b = bp >> 10, p = bp & 1023;
#pragma unroll
        for (int i = 0; i < 4; ++i) {
          int o = om + mt * 16 + qd * 4 + i;
          int h = o >> 5, d = o & 31;
          Yt[(((size_t)(b * 8 + h)) * 1024 + p) * 32 + d] = (short)f2bf(acc[mt][nt][i] * sc);
        }
        int ob = om + mt * 16 + qd * 4;
        bf16x4 h4, l4;
#pragma unroll
        for (int i = 0; i < 4; ++i) {
          float f = acc[mt][nt][i];
          unsigned short h = f2bf(f);
          h4[i] = (short)h;
          l4[i] = (short)f2bf(f - bf2f(h));
        }
        *(bf16x4*)&Yh2[(size_t)bp * 256 + ob] = h4;
        *(bf16x4*)&Yl2[(size_t)bp * 256 + ob] = l4;
      }

  } else if (bid < 768) {               // ---- kvT transpose ----
    int tb = bid - 512;
    int b = tb >> 5, p0 = (tb & 31) * 32;
    int pp = t & 31, cg = t >> 5;
#pragma unroll
    for (int i = 0; i < 32; ++i) {
      int c = cg * 32 + i;
      T[c][pp] = kv[((size_t)(b * 256 + c)) * HW_ + p0 + pp];
    }
    __syncthreads();
#pragma unroll
    for (int r = 0; r < 8; ++r) {
      int e = t + 256 * r;
      int c4 = (e & 63) * 4, pp2 = e >> 6;
      float4 v4;
      v4.x = T[c4 + 0][pp2];
      v4.y = T[c4 + 1][pp2];
      v4.z = T[c4 + 2][pp2];
      v4.w = T[c4 + 3][pp2];
      *(float4*)&kvT[((size_t)(b * 1024 + p0 + pp2)) * 256 + c4] = v4;
    }
  } else if (bid < 960) {               // ---- wsplit ----
    int b2 = bid - 768;
    int mat = b2 >> 6;
    int loc = (b2 & 63) * 1024 + t * 4;
    const float* W = (mat == 0) ? Wk : (mat == 1) ? Wv : Wo;
    float4 f4 = *(const float4*)&W[loc];
    float f[4] = {f4.x, f4.y, f4.z, f4.w};
    bf16x4 h4, l4;
#pragma unroll
    for (int j = 0; j < 4; ++j) {
      unsigned short h = f2bf(f[j]);
      h4[j] = (short)h;
      l4[j] = (short)f2bf(f[j] - bf2f(h));
    }
    if (mat == 2) {                     // Wout linear (slot 3)
      *(bf16x4*)&WH[3 * 65536 + loc] = h4;
      *(bf16x4*)&WL[3 * 65536 + loc] = l4;
    } else {                            // Wk/Wv packed fragment layout
      int r = loc >> 8, c = loc & 255;  // 4 consecutive c, same 8-group
      int mtile = r >> 4, k0s = c >> 5;
      int lane_ = ((c >> 3) & 3) * 16 + (r & 15);
      int pidx = (((mtile * 8 + k0s) * 64 + lane_) * 8) + (c & 7);
      *(bf16x4*)&WH[(mat + 1) * 65536 + pidx] = h4;
      *(bf16x4*)&WL[(mat + 1) * 65536 + pidx] = l4;
    }
  } else {                              // ---- conv weight repack (packed) ----
    int e0 = (bid - 960) * 1024 + t * 4;
    int c = e0 & 255;                   // 4 consecutive c, same 8-group
    int o = (e0 >> 8) & 127;
    int tap = e0 >> 15;
    bf16x4 h4;
#pragma unroll
    for (int j = 0; j < 4; ++j)
      h4[j] = (short)f2bf(Woff1[((size_t)(o * 256 + c + j)) * 9 + tap]);
    int otile = o >> 4, c0s = c >> 5;
    int lane_ = ((c >> 3) & 3) * 16 + (o & 15);
    int widx = ((((tap * 8 + otile) * 8 + c0s) * 64 + lane_) * 8) + (c & 7);
    *(bf16x4*)&wb[widx] = h4;
  }
}

// ---------------------------------------------------------------------------
// convkv v4 = v2 structure (512 thr, 8 waves -- the 44.8 us baseline) with
// PACKED weight loads: afr/Ah/Al are dense 1 KB wave-reads (base+lane*16B).
// grid 256 (b = id&7 -> XCD-local), LDS 139.5 KB, 1 block/CU.
// ---------------------------------------------------------------------------
__global__ __launch_bounds__(512) void convkv(
    const short* __restrict__ wb, const float* __restrict__ bias,
    const float* __restrict__ W2, const float* __restrict__ b2,
    const short* __restrict__ xh, const short* __restrict__ xl,
    const float* __restrict__ kvT,
    const short* __restrict__ WH, const short* __restrict__ WL,
    short* __restrict__ kt, short* __restrict__ vt)
{
  __shared__ short Xs[2][3][34][264];   // full strip, ch-pad 264 (528B rows)
  __shared__ short XsH[32][264];
  __shared__ short XsL[32][264];
  __shared__ float red[4][32][2];
  __shared__ float2 crd[32];
  const int id   = blockIdx.x;          // 256
  const int b    = id & 7;
  const int y0   = id >> 3;             // 0..31
  const int t    = threadIdx.x;
  const int w    = t >> 6;
  const int lane = t & 63;
  const int ln   = lane & 15;
  const int qd   = lane >> 4;
  const int bp0  = (b * 32 + y0) * 32;  // global pixel-row base

  // ---------------- phase 0: one-shot staging ----------------
  {
    bf16x8 v[12];
#pragma unroll
    for (int i = 0; i < 12; ++i) {      // 6144 tasks: hl,r,x,oct
      int e = t + 512 * i;
      int oct = e & 31;
      int x   = (e >> 5) & 31;
      int rr  = e >> 10;                // 0..5
      int hl  = rr / 3, r = rr % 3;
      int yy  = y0 + r - 1;
      bf16x8 val = {};
      if (yy >= 0 && yy < 32) {
        const short* src = hl ? xl : xh;
        val = *(const bf16x8*)&src[((size_t)((b * 32 + yy) * 32 + x)) * 256 + oct * 8];
      }
      v[i] = val;
    }
#pragma unroll
    for (int i = 0; i < 12; ++i) {
      int e = t + 512 * i;
      int oct = e & 31;
      int x   = (e >> 5) & 31;
      int rr  = e >> 10;
      int hl  = rr / 3, r = rr % 3;
      *(bf16x8*)&Xs[hl][r][x + 1][oct * 8] = v[i];
    }
    if (t < 384) {                      // zero columns x=0 and x=33
      int oct  = t & 31;
      int colw = (t >> 5) & 1;
      int rr   = t >> 6;                // 0..5
      int hl   = rr / 3, r = rr % 3;
      bf16x8 zz = {};
      *(bf16x8*)&Xs[hl][r][colw ? 33 : 0][oct * 8] = zz;
    }
  }
  __syncthreads();

  // ---------------- phase 1: conv3x3, c0-split across wave-halves ----------
  const int chh = w >> 2;               // c-half 0/1
  const int ow  = w & 3;
  const int o0c = ow * 32;              // 32 output channels per wave (m=0,1)
  f32x4 acc[2][2] = {};
#pragma unroll
  for (int c0s = 0; c0s < 4; ++c0s) {
    const int c0 = chh * 128 + c0s * 32;
    const int c0abs = chh * 4 + c0s;    // packed c-block index
#pragma unroll
    for (int tap = 0; tap < 9; ++tap) {
      const int ky = tap / 3, kx = tap % 3;
      bf16x8 afr[2];
#pragma unroll
      for (int m = 0; m < 2; ++m)       // packed: dense 1 KB wave-read
        afr[m] = *(const bf16x8*)&wb[((((tap * 8 + (ow * 2 + m)) * 8 + c0abs) * 64
                                       + lane) * 8)];
#pragma unroll
      for (int nt = 0; nt < 2; ++nt) {
        int hc = nt * 16 + ln + kx;
        bf16x8 bh = *(const bf16x8*)&Xs[0][ky][hc][c0 + qd * 8];
        bf16x8 bl = *(const bf16x8*)&Xs[1][ky][hc][c0 + qd * 8];
#pragma unroll
        for (int m = 0; m < 2; ++m) {
          acc[m][nt] = __builtin_amdgcn_mfma_f32_16x16x32_bf16(afr[m], bh, acc[m][nt], 0, 0, 0);
          acc[m][nt] = __builtin_amdgcn_mfma_f32_16x16x32_bf16(afr[m], bl, acc[m][nt], 0, 0, 0);
        }
      }
    }
  }

  // combine c-halves: waves 4-7 park partials in XsH overlay (16 KB)
  float* ps = (float*)&XsH[0][0];
  if (w >= 4) {
#pragma unroll
    for (int m = 0; m < 2; ++m)
#pragma unroll
      for (int nt = 0; nt < 2; ++nt)
        *(f32x4*)&ps[(((w - 4) * 64 + lane) * 4 + m * 2 + nt) * 4] = acc[m][nt];
  }
  __syncthreads();

  // ---------------- phase 2: offset head -> coords (waves 0-3) -------------
  if (w < 4) {
    float ps0[2] = {0.f, 0.f}, ps1[2] = {0.f, 0.f};
#pragma unroll
    for (int m = 0; m < 2; ++m)
#pragma unroll
      for (int nt = 0; nt < 2; ++nt) {
        f32x4 p = *(const f32x4*)&ps[((w * 64 + lane) * 4 + m * 2 + nt) * 4];
        acc[m][nt] += p;
      }
#pragma unroll
    for (int m = 0; m < 2; ++m)
#pragma unroll
      for (int i = 0; i < 4; ++i) {
        int o = o0c + m * 16 + qd * 4 + i;
        float bo = bias[o];
        float w2a = W2[o], w2b = W2[128 + o];
#pragma unroll
        for (int nt = 0; nt < 2; ++nt) {
          float h = fmaxf(acc[m][nt][i] + bo, 0.f);
          ps0[nt] += w2a * h;
          ps1[nt] += w2b * h;
        }
      }
#pragma unroll
    for (int msk = 16; msk < 64; msk <<= 1) {
      ps0[0] += __shfl_xor(ps0[0], msk, 64);
      ps0[1] += __shfl_xor(ps0[1], msk, 64);
      ps1[0] += __shfl_xor(ps1[0], msk, 64);
      ps1[1] += __shfl_xor(ps1[1], msk, 64);
    }
    if (qd == 0) {
#pragma unroll
      for (int nt = 0; nt < 2; ++nt) {
        red[w][nt * 16 + ln][0] = ps0[nt];
        red[w][nt * 16 + ln][1] = ps1[nt];
      }
    }
  }
  __syncthreads();
  if (t < 32) {
    float c0s = (red[0][t][0] + red[1][t][0]) + (red[2][t][0] + red[3][t][0]) + b2[0];
    float c1s = (red[0][t][1] + red[1][t][1]) + (red[2][t][1] + red[3][t][1]) + b2[1];
    float gx = -1.f + 2.f * (float)t / 31.f;
    float gy = -1.f + 2.f * (float)y0 / 31.f;
    float vx = gx + 0.1f * c0s;
    float vy = gy + 0.1f * c1s;
    float px = fminf(fmaxf((vx + 1.f) * 0.5f * 31.f, 0.f), 31.f);
    float py = fminf(fmaxf((vy + 1.f) * 0.5f * 31.f, 0.f), 31.f);
    crd[t] = make_float2(px, py);
  }
  __syncthreads();

  // ---------------- phase 3: sampling + K/V GEMM ----------------
#pragma unroll
  for (int it = 0; it < 2; ++it) {
    int e = t + 512 * it;              // 1024 tasks: 32 rows x 32 octs
    int oct = e & 31, row = e >> 5;
    float2 cd = crd[row];
    float x0f = floorf(cd.x), y0f = floorf(cd.y);
    float wx = cd.x - x0f, wy = cd.y - y0f;
    int x0 = (int)x0f, y0i = (int)y0f;
    int x1 = min(x0 + 1, 31), y1 = min(y0i + 1, 31);
    float w00 = (1.f - wx) * (1.f - wy), w01 = wx * (1.f - wy);
    float w10 = (1.f - wx) * wy,         w11 = wx * wy;
    const float* r00 = &kvT[((size_t)(b * 1024 + y0i * 32 + x0)) * 256 + oct * 8];
    const float* r01 = &kvT[((size_t)(b * 1024 + y0i * 32 + x1)) * 256 + oct * 8];
    const float* r10 = &kvT[((size_t)(b * 1024 + y1 * 32 + x0)) * 256 + oct * 8];
    const float* r11 = &kvT[((size_t)(b * 1024 + y1 * 32 + x1)) * 256 + oct * 8];
    float4 a00 = *(const float4*)r00, b00 = *(const float4*)(r00 + 4);
    float4 a01 = *(const float4*)r01, b01 = *(const float4*)(r01 + 4);
    float4 a10 = *(const float4*)r10, b10 = *(const float4*)(r10 + 4);
    float4 a11 = *(const float4*)r11, b11 = *(const float4*)(r11 + 4);
    float v[8];
    v[0] = a00.x * w00 + a01.x * w01 + a10.x * w10 + a11.x * w11;
    v[1] = a00.y * w00 + a01.y * w01 + a10.y * w10 + a11.y * w11;
    v[2] = a00.z * w00 + a01.z * w01 + a10.z * w10 + a11.z * w11;
    v[3] = a00.w * w00 + a01.w * w01 + a10.w * w10 + a11.w * w11;
    v[4] = b00.x * w00 + b01.x * w01 + b10.x * w10 + b11.x * w11;
    v[5] = b00.y * w00 + b01.y * w01 + b10.y * w10 + b11.y * w11;
    v[6] = b00.z * w00 + b01.z * w01 + b10.z * w10 + b11.z * w11;
    v[7] = b00.w * w00 + b01.w * w01 + b10.w * w10 + b11.w * w11;
    bf16x8 h8, l8;
#pragma unroll
    for (int j = 0; j < 8; ++j) {
      unsigned short h = f2bf(v[j]);
      h8[j] = (short)h;
      l8[j] = (short)f2bf(v[j] - bf2f(h));
    }
    *(bf16x8*)&XsH[row][oct * 8] = h8;
    *(bf16x8*)&XsL[row][oct * 8] = l8;
  }
  __syncthreads();

  const int mat  = w >> 2;             // waves 0-3 = K, 4-7 = V
  const short* WAh = WH + (mat ? 131072 : 65536);   // Wv : Wk (bf16 hi, packed)
  const short* WAl = WL + (mat ? 131072 : 65536);
  const int om4 = (w & 3) * 4;         // mtile base (wave covers 64 rows)

  f32x4 acg[4][2] = {};
#pragma unroll
  for (int k0 = 0; k0 < 256; k0 += 32) {
    const int k0s = k0 >> 5;
    bf16x8 Bh[2], Bl[2];
#pragma unroll
    for (int nt = 0; nt < 2; ++nt) {
      Bh[nt] = *(const bf16x8*)&XsH[nt * 16 + ln][k0 + qd * 8];
      Bl[nt] = *(const bf16x8*)&XsL[nt * 16 + ln][k0 + qd * 8];
    }
#pragma unroll
    for (int mt = 0; mt < 4; ++mt) {
      size_t wi = ((size_t)(((om4 + mt) * 8 + k0s) * 64 + lane)) * 8;  // packed
      bf16x8 Ah = *(const bf16x8*)&WAh[wi];
      bf16x8 Al = *(const bf16x8*)&WAl[wi];
#pragma unroll
      for (int nt = 0; nt < 2; ++nt) {
        acg[mt][nt] = __builtin_amdgcn_mfma_f32_16x16x32_bf16(Ah, Bh[nt], acg[mt][nt], 0, 0, 0);
        acg[mt][nt] = __builtin_amdgcn_mfma_f32_16x16x32_bf16(Ah, Bl[nt], acg[mt][nt], 0, 0, 0);
        acg[mt][nt] = __builtin_amdgcn_mfma_f32_16x16x32_bf16(Al, Bh[nt], acg[mt][nt], 0, 0, 0);
      }
    }
  }

#pragma unroll
  for (int mt = 0; mt < 4; ++mt)
#pragma unroll
    for (int nt = 0; nt < 2; ++nt) {
      int p  = bp0 + nt * 16 + ln;
      int pl = p & 1023;
      int jt = pl >> 6, jl = pl & 63;
#pragma unroll
      for (int i = 0; i < 4; ++i) {
        int oc = (w & 3) * 64 + mt * 16 + qd * 4 + i;
        unsigned short val = f2bf(acg[mt][nt][i]);
        int bhead = b * 8 + (oc >> 5), d = oc & 31;
        if (mat == 0) {
          int cd2 = (d >> 3) ^ ((jl >> 2) & 3);
          kt[((((size_t)(bhead * 16 + jt)) * 64 + jl) * 4 + cd2) * 8 + (d & 7)] = (short)val;
        } else {
          int jjs = ((jl & 15) << 2) | (jl >> 4);       // sigma
          int cj = (jjs >> 3) ^ (d & 7);
          vt[((((size_t)(bhead * 16 + jt)) * 32 + d) * 8 + cj) * 8 + (jjs & 7)] = (short)val;
        }
      }
    }
}

// ---------------------------------------------------------------------------
// MFMA flash attention, async LDS double-buffered K/V.
// 2x Q-TILE per wave; XCD swizzle b = id&7; setprio around MFMA clusters.
// ---------------------------------------------------------------------------
__global__ __launch_bounds__(256) void attn_mfma(
    const short* __restrict__ qt, const short* __restrict__ kt,
    const short* __restrict__ vt, short* __restrict__ aoh,
    short* __restrict__ aol)
{
  __shared__ __align__(16) short Ks[2][2048];
  __shared__ __align__(16) short Vs[2][2048];
  __shared__ __align__(16) short P[4][32][72];
  const int t    = threadIdx.x;
  const int w    = t >> 6;
  const int lane = t & 63;
  const int ln   = lane & 15;
  const int qd   = lane >> 4;
  const int id   = blockIdx.x;          // 512
  const int b    = id & 7;
  const int rem  = id >> 3;             // 0..63
  const int h    = rem & 7;
  const int qc   = rem >> 3;            // 0..7
  const int bh   = b * 8 + h;
  const int qbase = qc * 128 + w * 16;  // fragment 0; fragment 1 at +64

  const short* ktb = kt + (size_t)bh * 32768;
  const short* vtb = vt + (size_t)bh * 32768;

  bf16x8 aq[2];
  aq[0] = *(const bf16x8*)&qt[((size_t)(bh * 1024 + qbase + ln)) * 32 + qd * 8];
  aq[1] = *(const bf16x8*)&qt[((size_t)(bh * 1024 + qbase + 64 + ln)) * 32 + qd * 8];

  f32x4 acc[2][2] = {};
  float lacc[2][4] = {};
  const f32x4 zero = {0.f, 0.f, 0.f, 0.f};

  const int stoff = w * 512 + lane * 8;
  const int ldoff = w * 512;

  async_copy16(&ktb[stoff], &Ks[0][ldoff]);
  async_copy16(&vtb[stoff], &Vs[0][ldoff]);
  __syncthreads();

  for (int jt = 0; jt < 16; ++jt) {
    const int cur = jt & 1, nxt = cur ^ 1;
    if (jt < 15) {
      async_copy16(&ktb[(jt + 1) * 2048 + stoff], &Ks[nxt][ldoff]);
      async_copy16(&vtb[(jt + 1) * 2048 + stoff], &Vs[nxt][ldoff]);
    }

    bf16x8 bk[4], bv[2][2];
#pragma unroll
    for (int kk = 0; kk < 4; ++kk)
      bk[kk] = *(const bf16x8*)&Ks[cur][((kk * 16 + ln) * 4 + (qd ^ ((ln >> 2) & 3))) * 8];
#pragma unroll
    for (int kc = 0; kc < 2; ++kc)
#pragma unroll
      for (int ds = 0; ds < 2; ++ds)
        bv[kc][ds] = *(const bf16x8*)&Vs[cur][((ds * 16 + ln) * 8 + ((kc * 4 + qd) ^ (ln & 7))) * 8];

#pragma unroll
    for (int qf = 0; qf < 2; ++qf) {
      f32x4 s[4];
      __builtin_amdgcn_s_setprio(1);
#pragma unroll
      for (int kk = 0; kk < 4; ++kk)
        s[kk] = __builtin_amdgcn_mfma_f32_16x16x32_bf16(aq[qf], bk[kk], zero, 0, 0, 0);
      __builtin_amdgcn_s_setprio(0);

#pragma unroll
      for (int i = 0; i < 4; ++i) {
        float p0 = __builtin_amdgcn_exp2f(s[0][i]);
        float p1 = __builtin_amdgcn_exp2f(s[1][i]);
        float p2 = __builtin_amdgcn_exp2f(s[2][i]);
        float p3 = __builtin_amdgcn_exp2f(s[3][i]);
        s[0][i] = p0; s[1][i] = p1; s[2][i] = p2; s[3][i] = p3;
        lacc[qf][i] += (p0 + p1) + (p2 + p3);
      }
#pragma unroll
      for (int i = 0; i < 4; ++i) {
        bf16x4 p4;
#pragma unroll
        for (int kk = 0; kk < 4; ++kk) p4[kk] = (short)f2bf_fast(s[kk][i]);
        *(bf16x4*)&P[w][qf * 16 + qd * 4 + i][4 * ln] = p4;
      }
      __builtin_amdgcn_s_setprio(1);
#pragma unroll
      for (int kc = 0; kc < 2; ++kc) {
        bf16x8 ap = *(const bf16x8*)&P[w][qf * 16 + ln][kc * 32 + qd * 8];
#pragma unroll
        for (int ds = 0; ds < 2; ++ds)
          acc[qf][ds] = __builtin_amdgcn_mfma_f32_16x16x32_bf16(ap, bv[kc][ds], acc[qf][ds], 0, 0, 0);
      }
      __builtin_amdgcn_s_setprio(0);
    }

    __syncthreads();
  }

  const int bb = bh >> 3, hh2 = bh & 7;
#pragma unroll
  for (int qf = 0; qf < 2; ++qf)
#pragma unroll
    for (int i = 0; i < 4; ++i) {
      float l = lacc[qf][i];
      l += __shfl_xor(l, 1, 64);
      l += __shfl_xor(l, 2, 64);
      l += __shfl_xor(l, 4, 64);
      l += __shfl_xor(l, 8, 64);
      float inv = 1.f / l;
      int qrow = qbase + qf * 64 + qd * 4 + i;
#pragma unroll
      for (int ds = 0; ds < 2; ++ds) {
        float v = acc[qf][ds][i] * inv;
        unsigned short hv = f2bf(v);
        size_t idx = ((size_t)(bb * 1024 + qrow)) * 256 + hh2 * 32 + ds * 16 + ln;
        aoh[idx] = (short)hv;
        aol[idx] = (short)f2bf(v - bf2f(hv));
      }
    }
}

// ---------------------------------------------------------------------------
// Output GEMM (Wout), LDS-free, f32 out + bias. grid (256,2).
// ---------------------------------------------------------------------------
__global__ __launch_bounds__(256) void gemm_out(
    const short* __restrict__ Wh, const short* __restrict__ Wl,
    const short* __restrict__ Xh, const short* __restrict__ Xl,
    const float* __restrict__ bias, float* __restrict__ Yf)
{
  const int t    = threadIdx.x;
  const int w    = t >> 6;
  const int lane = t & 63;
  const int ln   = lane & 15;
  const int qd   = lane >> 4;
  const int bp0  = blockIdx.x * 32;
  const int om   = blockIdx.y * 128 + w * 32;

  f32x4 acc[2][2] = {};
#pragma unroll
  for (int k0 = 0; k0 < 256; k0 += 32) {
    bf16x8 Ah[2], Al[2], Bh[2], Bl[2];
#pragma unroll
    for (int mt = 0; mt < 2; ++mt) {
      size_t wi = ((size_t)(om + mt * 16 + ln)) * 256 + k0 + qd * 8;
      Ah[mt] = *(const bf16x8*)&Wh[wi];
      Al[mt] = *(const bf16x8*)&Wl[wi];
    }
#pragma unroll
    for (int nt = 0; nt < 2; ++nt) {
      size_t xi = ((size_t)(bp0 + nt * 16 + ln)) * 256 + k0 + qd * 8;
      Bh[nt] = *(const bf16x8*)&Xh[xi];
      Bl[nt] = *(const bf16x8*)&Xl[xi];
    }
#pragma unroll
    for (int mt = 0; mt < 2; ++mt)
#pragma unroll
      for (int nt = 0; nt < 2; ++nt) {
        acc[mt][nt] = __builtin_amdgcn_mfma_f32_16x16x32_bf16(Ah[mt], Bh[nt], acc[mt][nt], 0, 0, 0);
        acc[mt][nt] = __builtin_amdgcn_mfma_f32_16x16x32_bf16(Ah[mt], Bl[nt], acc[mt][nt], 0, 0, 0);
        acc[mt][nt] = __builtin_amdgcn_mfma_f32_16x16x32_bf16(Al[mt], Bh[nt], acc[mt][nt], 0, 0, 0);
      }
  }

#pragma unroll
  for (int mt = 0; mt < 2; ++mt)
#pragma unroll
    for (int i = 0; i < 4; ++i) {
      int o = om + mt * 16 + qd * 4 + i;
      float bo = bias[o];
#pragma unroll
      for (int nt = 0; nt < 2; ++nt) {
        int bp = bp0 + nt * 16 + ln;
        int b = bp >> 10, p = bp & 1023;
        Yf[((size_t)(b * 256 + o)) * HW_ + p] = acc[mt][nt][i] + bo;
      }
    }
}

// ---------------------------------------------------------------------------
extern "C" void kernel_launch(void* const* d_in, const int* in_sizes, int n_in,
                              void* d_out, int out_size, void* d_ws, size_t ws_size,
                              hipStream_t stream)
{
  const float* query_map = (const float*)d_in[0];
  const float* kv_map    = (const float*)d_in[1];
  const float* Wq        = (const float*)d_in[2];
  const float* Wk        = (const float*)d_in[3];
  const float* Wv        = (const float*)d_in[4];
  const float* Woff1     = (const float*)d_in[5];
  const float* boff1     = (const float*)d_in[6];
  const float* Woff2     = (const float*)d_in[7];
  const float* boff2     = (const float*)d_in[8];
  const float* Wout      = (const float*)d_in[9];
  const float* bout      = (const float*)d_in[10];
  float* out = (float*)d_out;
  char* base = (char*)d_ws;

  const size_t MB = 1u << 20;
  short* qt     = (short*)(base + 1 * MB);     // 4 MB (bh,p,d) pre-scaled
  short* kt     = (short*)(base + 5 * MB);     // 4 MB tiled+swizzled
  short* vt     = (short*)(base + 9 * MB);     // 4 MB tiled+swizzled
  short* bufBh  = (short*)(base + 13 * MB);    // 4 MB q hi -> ao hi
  short* bufBl  = (short*)(base + 17 * MB);    // 4 MB q lo -> ao lo
  short* wb     = (short*)(base + 21 * MB);    // 576 KB conv weights (packed)
  short* WH     = (short*)(base + 22 * MB);    // 512 KB [.|Wk^p|Wv^p|Wout] hi
  short* WL     = (short*)(base + 23 * MB);    // 512 KB lo
  float* kvT    = (float*)(base + 24 * MB);    // 8 MB kv_map (b,p,c) f32

  fused0<<<dim3(1248), dim3(256), 0, stream>>>(kv_map, Wq, Wk, Wv, Wout, Woff1,
                                               query_map, WH, WL, wb, kvT,
                                               qt, bufBh, bufBl);
  convkv<<<dim3(256), dim3(512), 0, stream>>>(wb, boff1, Woff2, boff2,
                                              bufBh, bufBl, kvT, WH, WL, kt, vt);
  attn_mfma<<<dim3(512), dim3(256), 0, stream>>>(qt, kt, vt, bufBh, bufBl);
  gemm_out<<<dim3(256, 2), dim3(256), 0, stream>>>(WH + 196608, WL + 196608,
                                                   bufBh, bufBl, bout, out);
}

// Round 7
// 161.940 us; speedup vs baseline: 1.2050x; 1.0559x over previous
//
#include <hip/hip_runtime.h>

#define HW_ 1024

typedef __attribute__((ext_vector_type(8))) short bf16x8;   // 8 bf16 = 4 VGPRs
typedef __attribute__((ext_vector_type(4))) short bf16x4;   // 8 B
typedef __attribute__((ext_vector_type(4))) float f32x4;

__device__ inline unsigned short f2bf(float f) {            // RNE f32->bf16
  unsigned int u = __float_as_uint(f);
  u += 0x7FFF + ((u >> 16) & 1);
  return (unsigned short)(u >> 16);
}
__device__ inline unsigned short f2bf_fast(float f) {       // ties-away (2 ops)
  return (unsigned short)((__float_as_uint(f) + 0x8000u) >> 16);
}
__device__ inline float bf2f(unsigned short h) {
  return __uint_as_float(((unsigned int)h) << 16);
}
__device__ inline void async_copy16(const void* g, void* l) {
  __builtin_amdgcn_global_load_lds(
      (const __attribute__((address_space(1))) unsigned int*)g,
      (__attribute__((address_space(3))) unsigned int*)l, 16, 0, 0);
}

// ---------------------------------------------------------------------------
// prep (grid 800): all one-time data marshalling, HBM-bound (~16 MB).
//   [0,256)   kvT transpose (b,c,p)->(b,p,c) f32.
//   [256,512) wsplit Wq/Wk/Wv/Wout -> PACKED fragment layout, slots 0..3.
//   [512,800) conv weight repack -> wb PACKED [tap][otile][c0s][lane][8].
// Packed layout (R6-proven): wave A-frag load = base + lane*16B, one dense
// 1 KB read instead of a 16-row x 64 B gather.
// Separated from qgemm so Wq is packed ONCE (fused version re-split it in
// all 512 blocks = 256x redundant VALU + gathers).
// ---------------------------------------------------------------------------
__global__ __launch_bounds__(256) void prep(
    const float* __restrict__ kv,
    const float* __restrict__ Wq, const float* __restrict__ Wk,
    const float* __restrict__ Wv, const float* __restrict__ Wo,
    const float* __restrict__ Woff1,
    short* __restrict__ WH, short* __restrict__ WL, short* __restrict__ wb,
    float* __restrict__ kvT)
{
  __shared__ float T[256][33];
  const int bid = blockIdx.x, t = threadIdx.x;

  if (bid < 256) {                      // ---- kvT transpose ----
    int b = bid >> 5, p0 = (bid & 31) * 32;
    int pp = t & 31, cg = t >> 5;
#pragma unroll
    for (int i = 0; i < 32; ++i) {
      int c = cg * 32 + i;
      T[c][pp] = kv[((size_t)(b * 256 + c)) * HW_ + p0 + pp];
    }
    __syncthreads();
#pragma unroll
    for (int r = 0; r < 8; ++r) {
      int e = t + 256 * r;
      int c4 = (e & 63) * 4, pp2 = e >> 6;
      float4 v4;
      v4.x = T[c4 + 0][pp2];
      v4.y = T[c4 + 1][pp2];
      v4.z = T[c4 + 2][pp2];
      v4.w = T[c4 + 3][pp2];
      *(float4*)&kvT[((size_t)(b * 1024 + p0 + pp2)) * 256 + c4] = v4;
    }
  } else if (bid < 512) {               // ---- wsplit, all packed ----
    int b2 = bid - 256;
    int mat = b2 >> 6;                  // 0..3 = Wq,Wk,Wv,Wout
    int loc = (b2 & 63) * 1024 + t * 4;
    const float* W = (mat == 0) ? Wq : (mat == 1) ? Wk : (mat == 2) ? Wv : Wo;
    float4 f4 = *(const float4*)&W[loc];
    float f[4] = {f4.x, f4.y, f4.z, f4.w};
    bf16x4 h4, l4;
#pragma unroll
    for (int j = 0; j < 4; ++j) {
      unsigned short h = f2bf(f[j]);
      h4[j] = (short)h;
      l4[j] = (short)f2bf(f[j] - bf2f(h));
    }
    int r = loc >> 8, c = loc & 255;    // 4 consecutive c in one 8-group
    int mtile = r >> 4, k0s = c >> 5;
    int lane_ = ((c >> 3) & 3) * 16 + (r & 15);
    int pidx = (((mtile * 8 + k0s) * 64 + lane_) * 8) + (c & 7);
    *(bf16x4*)&WH[mat * 65536 + pidx] = h4;
    *(bf16x4*)&WL[mat * 65536 + pidx] = l4;
  } else {                              // ---- conv weight repack (packed) ----
    int e0 = (bid - 512) * 1024 + t * 4;
    int c = e0 & 255;
    int o = (e0 >> 8) & 127;
    int tap = e0 >> 15;
    bf16x4 h4;
#pragma unroll
    for (int j = 0; j < 4; ++j)
      h4[j] = (short)f2bf(Woff1[((size_t)(o * 256 + c + j)) * 9 + tap]);
    int otile = o >> 4, c0s = c >> 5;
    int lane_ = ((c >> 3) & 3) * 16 + (o & 15);
    int widx = ((((tap * 8 + otile) * 8 + c0s) * 64 + lane_) * 8) + (c & 7);
    *(bf16x4*)&wb[widx] = h4;
  }
}

// ---------------------------------------------------------------------------
// qgemm: Q projection, M=256 K=256 N=8192, packed-Wq A-frags (dense 16B/lane,
// ZERO split VALU), X staged+split through LDS per k-step. grid (256,2).
// Outputs qt (bh,p,d)*log2e/sqrt32 + q hi/lo (b,p,c).
// ---------------------------------------------------------------------------
__global__ __launch_bounds__(256) void qgemm(
    const short* __restrict__ WH, const short* __restrict__ WL,
    const float* __restrict__ Xf,
    short* __restrict__ Yt, short* __restrict__ Yh2, short* __restrict__ Yl2)
{
  __shared__ short Bsh[32][40];
  __shared__ short Bsl[32][40];
  const int t    = threadIdx.x;
  const int w    = t >> 6;
  const int lane = t & 63;
  const int ln   = lane & 15;
  const int qd   = lane >> 4;
  const int bp0  = blockIdx.x * 32;
  const int mb   = blockIdx.y * 8 + w * 2;    // mtile base (16-row tiles)
  const int bB   = bp0 >> 10, p0l = bp0 & 1023;

  f32x4 acc[2][2] = {};
#pragma unroll
  for (int k0 = 0; k0 < 256; k0 += 32) {
    __syncthreads();
    {                                   // stage + split X tile
      int pp = t & 31, cg = t >> 5;
      float fv[4];
#pragma unroll
      for (int j = 0; j < 4; ++j)
        fv[j] = Xf[((size_t)(bB * 256 + k0 + cg * 4 + j)) * HW_ + p0l + pp];
      bf16x4 h4, l4;
#pragma unroll
      for (int j = 0; j < 4; ++j) {
        unsigned short h = f2bf(fv[j]);
        h4[j] = (short)h;
        l4[j] = (short)f2bf(fv[j] - bf2f(h));
      }
      *(bf16x4*)&Bsh[pp][cg * 4] = h4;
      *(bf16x4*)&Bsl[pp][cg * 4] = l4;
    }
    __syncthreads();

    bf16x8 Ah[2], Al[2], Bh[2], Bl[2];
    const int k0s = k0 >> 5;
#pragma unroll
    for (int mt = 0; mt < 2; ++mt) {    // packed: dense 1 KB wave-read
      size_t wi = ((size_t)(((mb + mt) * 8 + k0s) * 64 + lane)) * 8;
      Ah[mt] = *(const bf16x8*)&WH[wi];
      Al[mt] = *(const bf16x8*)&WL[wi];
    }
#pragma unroll
    for (int nt = 0; nt < 2; ++nt) {
      Bh[nt] = *(const bf16x8*)&Bsh[nt * 16 + ln][qd * 8];
      Bl[nt] = *(const bf16x8*)&Bsl[nt * 16 + ln][qd * 8];
    }
#pragma unroll
    for (int mt = 0; mt < 2; ++mt)
#pragma unroll
      for (int nt = 0; nt < 2; ++nt) {
        acc[mt][nt] = __builtin_amdgcn_mfma_f32_16x16x32_bf16(Ah[mt], Bh[nt], acc[mt][nt], 0, 0, 0);
        acc[mt][nt] = __builtin_amdgcn_mfma_f32_16x16x32_bf16(Ah[mt], Bl[nt], acc[mt][nt], 0, 0, 0);
        acc[mt][nt] = __builtin_amdgcn_mfma_f32_16x16x32_bf16(Al[mt], Bh[nt], acc[mt][nt], 0, 0, 0);
      }
  }

  const int om = blockIdx.y * 128 + w * 32;
  const float sc = 0.25506063286f;      // (1/sqrt32)*log2(e)
#pragma unroll
  for (int mt = 0; mt < 2; ++mt)
#pragma unroll
    for (int nt = 0; nt < 2; ++nt) {
      int bp = bp0 + nt * 16 + ln;
      int b = bp >> 10, p = bp & 1023;
#pragma unroll
      for (int i = 0; i < 4; ++i) {
        int o = om + mt * 16 + qd * 4 + i;
        int h = o >> 5, d = o & 31;
        Yt[(((size_t)(b * 8 + h)) * 1024 + p) * 32 + d] = (short)f2bf(acc[mt][nt][i] * sc);
      }
      int ob = om + mt * 16 + qd * 4;
      bf16x4 h4, l4;
#pragma unroll
      for (int i = 0; i < 4; ++i) {
        float f = acc[mt][nt][i];
        unsigned short h = f2bf(f);
        h4[i] = (short)h;
        l4[i] = (short)f2bf(f - bf2f(h));
      }
      *(bf16x4*)&Yh2[(size_t)bp * 256 + ob] = h4;
      *(bf16x4*)&Yl2[(size_t)bp * 256 + ob] = l4;
    }
}

// ---------------------------------------------------------------------------
// convkv (unchanged from R6, 171 us pipeline): one-shot staging + c0-split
// conv + offset head + sampling + K/V GEMM with packed weights.
// ---------------------------------------------------------------------------
__global__ __launch_bounds__(512) void convkv(
    const short* __restrict__ wb, const float* __restrict__ bias,
    const float* __restrict__ W2, const float* __restrict__ b2,
    const short* __restrict__ xh, const short* __restrict__ xl,
    const float* __restrict__ kvT,
    const short* __restrict__ WH, const short* __restrict__ WL,
    short* __restrict__ kt, short* __restrict__ vt)
{
  __shared__ short Xs[2][3][34][264];
  __shared__ short XsH[32][264];
  __shared__ short XsL[32][264];
  __shared__ float red[4][32][2];
  __shared__ float2 crd[32];
  const int id   = blockIdx.x;          // 256
  const int b    = id & 7;
  const int y0   = id >> 3;
  const int t    = threadIdx.x;
  const int w    = t >> 6;
  const int lane = t & 63;
  const int ln   = lane & 15;
  const int qd   = lane >> 4;
  const int bp0  = (b * 32 + y0) * 32;

  // phase 0: one-shot staging
  {
    bf16x8 v[12];
#pragma unroll
    for (int i = 0; i < 12; ++i) {
      int e = t + 512 * i;
      int oct = e & 31;
      int x   = (e >> 5) & 31;
      int rr  = e >> 10;
      int hl  = rr / 3, r = rr % 3;
      int yy  = y0 + r - 1;
      bf16x8 val = {};
      if (yy >= 0 && yy < 32) {
        const short* src = hl ? xl : xh;
        val = *(const bf16x8*)&src[((size_t)((b * 32 + yy) * 32 + x)) * 256 + oct * 8];
      }
      v[i] = val;
    }
#pragma unroll
    for (int i = 0; i < 12; ++i) {
      int e = t + 512 * i;
      int oct = e & 31;
      int x   = (e >> 5) & 31;
      int rr  = e >> 10;
      int hl  = rr / 3, r = rr % 3;
      *(bf16x8*)&Xs[hl][r][x + 1][oct * 8] = v[i];
    }
    if (t < 384) {
      int oct  = t & 31;
      int colw = (t >> 5) & 1;
      int rr   = t >> 6;
      int hl   = rr / 3, r = rr % 3;
      bf16x8 zz = {};
      *(bf16x8*)&Xs[hl][r][colw ? 33 : 0][oct * 8] = zz;
    }
  }
  __syncthreads();

  // phase 1: conv3x3, c0-split across wave-halves
  const int chh = w >> 2;
  const int ow  = w & 3;
  const int o0c = ow * 32;
  f32x4 acc[2][2] = {};
#pragma unroll
  for (int c0s = 0; c0s < 4; ++c0s) {
    const int c0 = chh * 128 + c0s * 32;
    const int c0abs = chh * 4 + c0s;
#pragma unroll
    for (int tap = 0; tap < 9; ++tap) {
      const int ky = tap / 3, kx = tap % 3;
      bf16x8 afr[2];
#pragma unroll
      for (int m = 0; m < 2; ++m)
        afr[m] = *(const bf16x8*)&wb[((((tap * 8 + (ow * 2 + m)) * 8 + c0abs) * 64
                                       + lane) * 8)];
#pragma unroll
      for (int nt = 0; nt < 2; ++nt) {
        int hc = nt * 16 + ln + kx;
        bf16x8 bh = *(const bf16x8*)&Xs[0][ky][hc][c0 + qd * 8];
        bf16x8 bl = *(const bf16x8*)&Xs[1][ky][hc][c0 + qd * 8];
#pragma unroll
        for (int m = 0; m < 2; ++m) {
          acc[m][nt] = __builtin_amdgcn_mfma_f32_16x16x32_bf16(afr[m], bh, acc[m][nt], 0, 0, 0);
          acc[m][nt] = __builtin_amdgcn_mfma_f32_16x16x32_bf16(afr[m], bl, acc[m][nt], 0, 0, 0);
        }
      }
    }
  }

  float* ps = (float*)&XsH[0][0];
  if (w >= 4) {
#pragma unroll
    for (int m = 0; m < 2; ++m)
#pragma unroll
      for (int nt = 0; nt < 2; ++nt)
        *(f32x4*)&ps[(((w - 4) * 64 + lane) * 4 + m * 2 + nt) * 4] = acc[m][nt];
  }
  __syncthreads();

  // phase 2: offset head -> coords
  if (w < 4) {
    float ps0[2] = {0.f, 0.f}, ps1[2] = {0.f, 0.f};
#pragma unroll
    for (int m = 0; m < 2; ++m)
#pragma unroll
      for (int nt = 0; nt < 2; ++nt) {
        f32x4 p = *(const f32x4*)&ps[((w * 64 + lane) * 4 + m * 2 + nt) * 4];
        acc[m][nt] += p;
      }
#pragma unroll
    for (int m = 0; m < 2; ++m)
#pragma unroll
      for (int i = 0; i < 4; ++i) {
        int o = o0c + m * 16 + qd * 4 + i;
        float bo = bias[o];
        float w2a = W2[o], w2b = W2[128 + o];
#pragma unroll
        for (int nt = 0; nt < 2; ++nt) {
          float h = fmaxf(acc[m][nt][i] + bo, 0.f);
          ps0[nt] += w2a * h;
          ps1[nt] += w2b * h;
        }
      }
#pragma unroll
    for (int msk = 16; msk < 64; msk <<= 1) {
      ps0[0] += __shfl_xor(ps0[0], msk, 64);
      ps0[1] += __shfl_xor(ps0[1], msk, 64);
      ps1[0] += __shfl_xor(ps1[0], msk, 64);
      ps1[1] += __shfl_xor(ps1[1], msk, 64);
    }
    if (qd == 0) {
#pragma unroll
      for (int nt = 0; nt < 2; ++nt) {
        red[w][nt * 16 + ln][0] = ps0[nt];
        red[w][nt * 16 + ln][1] = ps1[nt];
      }
    }
  }
  __syncthreads();
  if (t < 32) {
    float c0s = (red[0][t][0] + red[1][t][0]) + (red[2][t][0] + red[3][t][0]) + b2[0];
    float c1s = (red[0][t][1] + red[1][t][1]) + (red[2][t][1] + red[3][t][1]) + b2[1];
    float gx = -1.f + 2.f * (float)t / 31.f;
    float gy = -1.f + 2.f * (float)y0 / 31.f;
    float vx = gx + 0.1f * c0s;
    float vy = gy + 0.1f * c1s;
    float px = fminf(fmaxf((vx + 1.f) * 0.5f * 31.f, 0.f), 31.f);
    float py = fminf(fmaxf((vy + 1.f) * 0.5f * 31.f, 0.f), 31.f);
    crd[t] = make_float2(px, py);
  }
  __syncthreads();

  // phase 3: sampling + K/V GEMM
#pragma unroll
  for (int it = 0; it < 2; ++it) {
    int e = t + 512 * it;
    int oct = e & 31, row = e >> 5;
    float2 cd = crd[row];
    float x0f = floorf(cd.x), y0f = floorf(cd.y);
    float wx = cd.x - x0f, wy = cd.y - y0f;
    int x0 = (int)x0f, y0i = (int)y0f;
    int x1 = min(x0 + 1, 31), y1 = min(y0i + 1, 31);
    float w00 = (1.f - wx) * (1.f - wy), w01 = wx * (1.f - wy);
    float w10 = (1.f - wx) * wy,         w11 = wx * wy;
    const float* r00 = &kvT[((size_t)(b * 1024 + y0i * 32 + x0)) * 256 + oct * 8];
    const float* r01 = &kvT[((size_t)(b * 1024 + y0i * 32 + x1)) * 256 + oct * 8];
    const float* r10 = &kvT[((size_t)(b * 1024 + y1 * 32 + x0)) * 256 + oct * 8];
    const float* r11 = &kvT[((size_t)(b * 1024 + y1 * 32 + x1)) * 256 + oct * 8];
    float4 a00 = *(const float4*)r00, b00 = *(const float4*)(r00 + 4);
    float4 a01 = *(const float4*)r01, b01 = *(const float4*)(r01 + 4);
    float4 a10 = *(const float4*)r10, b10 = *(const float4*)(r10 + 4);
    float4 a11 = *(const float4*)r11, b11 = *(const float4*)(r11 + 4);
    float v[8];
    v[0] = a00.x * w00 + a01.x * w01 + a10.x * w10 + a11.x * w11;
    v[1] = a00.y * w00 + a01.y * w01 + a10.y * w10 + a11.y * w11;
    v[2] = a00.z * w00 + a01.z * w01 + a10.z * w10 + a11.z * w11;
    v[3] = a00.w * w00 + a01.w * w01 + a10.w * w10 + a11.w * w11;
    v[4] = b00.x * w00 + b01.x * w01 + b10.x * w10 + b11.x * w11;
    v[5] = b00.y * w00 + b01.y * w01 + b10.y * w10 + b11.y * w11;
    v[6] = b00.z * w00 + b01.z * w01 + b10.z * w10 + b11.z * w11;
    v[7] = b00.w * w00 + b01.w * w01 + b10.w * w10 + b11.w * w11;
    bf16x8 h8, l8;
#pragma unroll
    for (int j = 0; j < 8; ++j) {
      unsigned short h = f2bf(v[j]);
      h8[j] = (short)h;
      l8[j] = (short)f2bf(v[j] - bf2f(h));
    }
    *(bf16x8*)&XsH[row][oct * 8] = h8;
    *(bf16x8*)&XsL[row][oct * 8] = l8;
  }
  __syncthreads();

  const int mat  = w >> 2;
  const short* WAh = WH + (mat ? 131072 : 65536);
  const short* WAl = WL + (mat ? 131072 : 65536);
  const int om4 = (w & 3) * 4;

  f32x4 acg[4][2] = {};
#pragma unroll
  for (int k0 = 0; k0 < 256; k0 += 32) {
    const int k0s = k0 >> 5;
    bf16x8 Bh[2], Bl[2];
#pragma unroll
    for (int nt = 0; nt < 2; ++nt) {
      Bh[nt] = *(const bf16x8*)&XsH[nt * 16 + ln][k0 + qd * 8];
      Bl[nt] = *(const bf16x8*)&XsL[nt * 16 + ln][k0 + qd * 8];
    }
#pragma unroll
    for (int mt = 0; mt < 4; ++mt) {
      size_t wi = ((size_t)(((om4 + mt) * 8 + k0s) * 64 + lane)) * 8;
      bf16x8 Ah = *(const bf16x8*)&WAh[wi];
      bf16x8 Al = *(const bf16x8*)&WAl[wi];
#pragma unroll
      for (int nt = 0; nt < 2; ++nt) {
        acg[mt][nt] = __builtin_amdgcn_mfma_f32_16x16x32_bf16(Ah, Bh[nt], acg[mt][nt], 0, 0, 0);
        acg[mt][nt] = __builtin_amdgcn_mfma_f32_16x16x32_bf16(Ah, Bl[nt], acg[mt][nt], 0, 0, 0);
        acg[mt][nt] = __builtin_amdgcn_mfma_f32_16x16x32_bf16(Al, Bh[nt], acg[mt][nt], 0, 0, 0);
      }
    }
  }

#pragma unroll
  for (int mt = 0; mt < 4; ++mt)
#pragma unroll
    for (int nt = 0; nt < 2; ++nt) {
      int p  = bp0 + nt * 16 + ln;
      int pl = p & 1023;
      int jt = pl >> 6, jl = pl & 63;
#pragma unroll
      for (int i = 0; i < 4; ++i) {
        int oc = (w & 3) * 64 + mt * 16 + qd * 4 + i;
        unsigned short val = f2bf(acg[mt][nt][i]);
        int bhead = b * 8 + (oc >> 5), d = oc & 31;
        if (mat == 0) {
          int cd2 = (d >> 3) ^ ((jl >> 2) & 3);
          kt[((((size_t)(bhead * 16 + jt)) * 64 + jl) * 4 + cd2) * 8 + (d & 7)] = (short)val;
        } else {
          int jjs = ((jl & 15) << 2) | (jl >> 4);       // sigma
          int cj = (jjs >> 3) ^ (d & 7);
          vt[((((size_t)(bhead * 16 + jt)) * 32 + d) * 8 + cj) * 8 + (jjs & 7)] = (short)val;
        }
      }
    }
}

// ---------------------------------------------------------------------------
// MFMA flash attention (unchanged from R6).
// ---------------------------------------------------------------------------
__global__ __launch_bounds__(256) void attn_mfma(
    const short* __restrict__ qt, const short* __restrict__ kt,
    const short* __restrict__ vt, short* __restrict__ aoh,
    short* __restrict__ aol)
{
  __shared__ __align__(16) short Ks[2][2048];
  __shared__ __align__(16) short Vs[2][2048];
  __shared__ __align__(16) short P[4][32][72];
  const int t    = threadIdx.x;
  const int w    = t >> 6;
  const int lane = t & 63;
  const int ln   = lane & 15;
  const int qd   = lane >> 4;
  const int id   = blockIdx.x;          // 512
  const int b    = id & 7;
  const int rem  = id >> 3;
  const int h    = rem & 7;
  const int qc   = rem >> 3;
  const int bh   = b * 8 + h;
  const int qbase = qc * 128 + w * 16;

  const short* ktb = kt + (size_t)bh * 32768;
  const short* vtb = vt + (size_t)bh * 32768;

  bf16x8 aq[2];
  aq[0] = *(const bf16x8*)&qt[((size_t)(bh * 1024 + qbase + ln)) * 32 + qd * 8];
  aq[1] = *(const bf16x8*)&qt[((size_t)(bh * 1024 + qbase + 64 + ln)) * 32 + qd * 8];

  f32x4 acc[2][2] = {};
  float lacc[2][4] = {};
  const f32x4 zero = {0.f, 0.f, 0.f, 0.f};

  const int stoff = w * 512 + lane * 8;
  const int ldoff = w * 512;

  async_copy16(&ktb[stoff], &Ks[0][ldoff]);
  async_copy16(&vtb[stoff], &Vs[0][ldoff]);
  __syncthreads();

  for (int jt = 0; jt < 16; ++jt) {
    const int cur = jt & 1, nxt = cur ^ 1;
    if (jt < 15) {
      async_copy16(&ktb[(jt + 1) * 2048 + stoff], &Ks[nxt][ldoff]);
      async_copy16(&vtb[(jt + 1) * 2048 + stoff], &Vs[nxt][ldoff]);
    }

    bf16x8 bk[4], bv[2][2];
#pragma unroll
    for (int kk = 0; kk < 4; ++kk)
      bk[kk] = *(const bf16x8*)&Ks[cur][((kk * 16 + ln) * 4 + (qd ^ ((ln >> 2) & 3))) * 8];
#pragma unroll
    for (int kc = 0; kc < 2; ++kc)
#pragma unroll
      for (int ds = 0; ds < 2; ++ds)
        bv[kc][ds] = *(const bf16x8*)&Vs[cur][((ds * 16 + ln) * 8 + ((kc * 4 + qd) ^ (ln & 7))) * 8];

#pragma unroll
    for (int qf = 0; qf < 2; ++qf) {
      f32x4 s[4];
      __builtin_amdgcn_s_setprio(1);
#pragma unroll
      for (int kk = 0; kk < 4; ++kk)
        s[kk] = __builtin_amdgcn_mfma_f32_16x16x32_bf16(aq[qf], bk[kk], zero, 0, 0, 0);
      __builtin_amdgcn_s_setprio(0);

#pragma unroll
      for (int i = 0; i < 4; ++i) {
        float p0 = __builtin_amdgcn_exp2f(s[0][i]);
        float p1 = __builtin_amdgcn_exp2f(s[1][i]);
        float p2 = __builtin_amdgcn_exp2f(s[2][i]);
        float p3 = __builtin_amdgcn_exp2f(s[3][i]);
        s[0][i] = p0; s[1][i] = p1; s[2][i] = p2; s[3][i] = p3;
        lacc[qf][i] += (p0 + p1) + (p2 + p3);
      }
#pragma unroll
      for (int i = 0; i < 4; ++i) {
        bf16x4 p4;
#pragma unroll
        for (int kk = 0; kk < 4; ++kk) p4[kk] = (short)f2bf_fast(s[kk][i]);
        *(bf16x4*)&P[w][qf * 16 + qd * 4 + i][4 * ln] = p4;
      }
      __builtin_amdgcn_s_setprio(1);
#pragma unroll
      for (int kc = 0; kc < 2; ++kc) {
        bf16x8 ap = *(const bf16x8*)&P[w][qf * 16 + ln][kc * 32 + qd * 8];
#pragma unroll
        for (int ds = 0; ds < 2; ++ds)
          acc[qf][ds] = __builtin_amdgcn_mfma_f32_16x16x32_bf16(ap, bv[kc][ds], acc[qf][ds], 0, 0, 0);
      }
      __builtin_amdgcn_s_setprio(0);
    }

    __syncthreads();
  }

  const int bb = bh >> 3, hh2 = bh & 7;
#pragma unroll
  for (int qf = 0; qf < 2; ++qf)
#pragma unroll
    for (int i = 0; i < 4; ++i) {
      float l = lacc[qf][i];
      l += __shfl_xor(l, 1, 64);
      l += __shfl_xor(l, 2, 64);
      l += __shfl_xor(l, 4, 64);
      l += __shfl_xor(l, 8, 64);
      float inv = 1.f / l;
      int qrow = qbase + qf * 64 + qd * 4 + i;
#pragma unroll
      for (int ds = 0; ds < 2; ++ds) {
        float v = acc[qf][ds][i] * inv;
        unsigned short hv = f2bf(v);
        size_t idx = ((size_t)(bb * 1024 + qrow)) * 256 + hh2 * 32 + ds * 16 + ln;
        aoh[idx] = (short)hv;
        aol[idx] = (short)f2bf(v - bf2f(hv));
      }
    }
}

// ---------------------------------------------------------------------------
// Output GEMM (Wout): PACKED A-frags (dense 16B/lane) + X staged through LDS
// with fully-coalesced row reads (one pixel row = contiguous 512 B).
// grid (256,2); LDS 33 KB -> 2 blocks/CU.
// ---------------------------------------------------------------------------
__global__ __launch_bounds__(256) void gemm_out(
    const short* __restrict__ Wh, const short* __restrict__ Wl,
    const short* __restrict__ Xh, const short* __restrict__ Xl,
    const float* __restrict__ bias, float* __restrict__ Yf)
{
  __shared__ short XsH[32][264];
  __shared__ short XsL[32][264];
  const int t    = threadIdx.x;
  const int w    = t >> 6;
  const int lane = t & 63;
  const int ln   = lane & 15;
  const int qd   = lane >> 4;
  const int bp0  = blockIdx.x * 32;
  const int mb   = blockIdx.y * 8 + w * 2;    // mtile base

#pragma unroll
  for (int it = 0; it < 4; ++it) {      // stage X tile: 1024 dense 16B loads
    int e = t + 256 * it;
    int oct = e & 31, row = e >> 5;
    bf16x8 vh = *(const bf16x8*)&Xh[((size_t)(bp0 + row)) * 256 + oct * 8];
    bf16x8 vl = *(const bf16x8*)&Xl[((size_t)(bp0 + row)) * 256 + oct * 8];
    *(bf16x8*)&XsH[row][oct * 8] = vh;
    *(bf16x8*)&XsL[row][oct * 8] = vl;
  }
  __syncthreads();

  f32x4 acc[2][2] = {};
#pragma unroll
  for (int k0 = 0; k0 < 256; k0 += 32) {
    const int k0s = k0 >> 5;
    bf16x8 Ah[2], Al[2], Bh[2], Bl[2];
#pragma unroll
    for (int mt = 0; mt < 2; ++mt) {    // packed: dense 1 KB wave-read
      size_t wi = ((size_t)(((mb + mt) * 8 + k0s) * 64 + lane)) * 8;
      Ah[mt] = *(const bf16x8*)&Wh[wi];
      Al[mt] = *(const bf16x8*)&Wl[wi];
    }
#pragma unroll
    for (int nt = 0; nt < 2; ++nt) {
      Bh[nt] = *(const bf16x8*)&XsH[nt * 16 + ln][k0 + qd * 8];
      Bl[nt] = *(const bf16x8*)&XsL[nt * 16 + ln][k0 + qd * 8];
    }
#pragma unroll
    for (int mt = 0; mt < 2; ++mt)
#pragma unroll
      for (int nt = 0; nt < 2; ++nt) {
        acc[mt][nt] = __builtin_amdgcn_mfma_f32_16x16x32_bf16(Ah[mt], Bh[nt], acc[mt][nt], 0, 0, 0);
        acc[mt][nt] = __builtin_amdgcn_mfma_f32_16x16x32_bf16(Ah[mt], Bl[nt], acc[mt][nt], 0, 0, 0);
        acc[mt][nt] = __builtin_amdgcn_mfma_f32_16x16x32_bf16(Al[mt], Bh[nt], acc[mt][nt], 0, 0, 0);
      }
  }

  const int om = blockIdx.y * 128 + w * 32;
#pragma unroll
  for (int mt = 0; mt < 2; ++mt)
#pragma unroll
    for (int i = 0; i < 4; ++i) {
      int o = om + mt * 16 + qd * 4 + i;
      float bo = bias[o];
#pragma unroll
      for (int nt = 0; nt < 2; ++nt) {
        int bp = bp0 + nt * 16 + ln;
        int b = bp >> 10, p = bp & 1023;
        Yf[((size_t)(b * 256 + o)) * HW_ + p] = acc[mt][nt][i] + bo;
      }
    }
}

// ---------------------------------------------------------------------------
extern "C" void kernel_launch(void* const* d_in, const int* in_sizes, int n_in,
                              void* d_out, int out_size, void* d_ws, size_t ws_size,
                              hipStream_t stream)
{
  const float* query_map = (const float*)d_in[0];
  const float* kv_map    = (const float*)d_in[1];
  const float* Wq        = (const float*)d_in[2];
  const float* Wk        = (const float*)d_in[3];
  const float* Wv        = (const float*)d_in[4];
  const float* Woff1     = (const float*)d_in[5];
  const float* boff1     = (const float*)d_in[6];
  const float* Woff2     = (const float*)d_in[7];
  const float* boff2     = (const float*)d_in[8];
  const float* Wout      = (const float*)d_in[9];
  const float* bout      = (const float*)d_in[10];
  float* out = (float*)d_out;
  char* base = (char*)d_ws;

  const size_t MB = 1u << 20;
  short* qt     = (short*)(base + 1 * MB);     // 4 MB (bh,p,d) pre-scaled
  short* kt     = (short*)(base + 5 * MB);     // 4 MB tiled+swizzled
  short* vt     = (short*)(base + 9 * MB);     // 4 MB tiled+swizzled
  short* bufBh  = (short*)(base + 13 * MB);    // 4 MB q hi -> ao hi
  short* bufBl  = (short*)(base + 17 * MB);    // 4 MB q lo -> ao lo
  short* wb     = (short*)(base + 21 * MB);    // 576 KB conv weights (packed)
  short* WH     = (short*)(base + 22 * MB);    // 512 KB [Wq|Wk|Wv|Wout] packed hi
  short* WL     = (short*)(base + 23 * MB);    // 512 KB lo
  float* kvT    = (float*)(base + 24 * MB);    // 8 MB kv_map (b,p,c) f32

  prep<<<dim3(800), dim3(256), 0, stream>>>(kv_map, Wq, Wk, Wv, Wout, Woff1,
                                            WH, WL, wb, kvT);
  qgemm<<<dim3(256, 2), dim3(256), 0, stream>>>(WH, WL, query_map,
                                                qt, bufBh, bufBl);
  convkv<<<dim3(256), dim3(512), 0, stream>>>(wb, boff1, Woff2, boff2,
                                              bufBh, bufBl, kvT, WH, WL, kt, vt);
  attn_mfma<<<dim3(512), dim3(256), 0, stream>>>(qt, kt, vt, bufBh, bufBl);
  gemm_out<<<dim3(256, 2), dim3(256), 0, stream>>>(WH + 196608, WL + 196608,
                                                   bufBh, bufBl, bout, out);
}